// Round 3
// baseline (3937.433 us; speedup 1.0000x reference)
//
#include <hip/hip_runtime.h>
#include <math.h>

#define D 128
#define EPSF 1e-9f

// ---------------- keys = prev @ attn_W + attn_b  [N,128] ----------------
__global__ __launch_bounds__(256, 2) void keys_kernel(
    const float* __restrict__ prev, const float* __restrict__ attn_W,
    const float* __restrict__ attn_b, float* __restrict__ keys, int N)
{
    __shared__ float Wl[D * D];       // 64 KB
    __shared__ float bl[D];
    __shared__ float rows[16][D];     // 8 KB

    for (int i = threadIdx.x; i < D * D / 4; i += 256)
        ((float4*)Wl)[i] = ((const float4*)attn_W)[i];
    if (threadIdx.x < D) bl[threadIdx.x] = attn_b[threadIdx.x];

    const int l = threadIdx.x & 31;
    const int r = threadIdx.x >> 5;
    const float4* W4 = (const float4*)Wl;

    for (int base = blockIdx.x * 16; base < N; base += gridDim.x * 16) {
        __syncthreads();
        int navail = N - base; if (navail > 16) navail = 16;
        for (int i = threadIdx.x; i < navail * (D / 4); i += 256)
            ((float4*)rows)[i] = ((const float4*)(prev + (size_t)base * D))[i];
        __syncthreads();

        float4 acc0 = ((const float4*)bl)[l];
        float4 acc1 = acc0;
        #pragma unroll 8
        for (int d = 0; d < D; ++d) {
            float4 w = W4[d * 32 + l];
            float p0 = rows[r][d];
            float p1 = rows[r + 8][d];
            acc0.x = fmaf(p0, w.x, acc0.x); acc0.y = fmaf(p0, w.y, acc0.y);
            acc0.z = fmaf(p0, w.z, acc0.z); acc0.w = fmaf(p0, w.w, acc0.w);
            acc1.x = fmaf(p1, w.x, acc1.x); acc1.y = fmaf(p1, w.y, acc1.y);
            acc1.z = fmaf(p1, w.z, acc1.z); acc1.w = fmaf(p1, w.w, acc1.w);
        }
        if (base + r < N)
            ((float4*)(keys + (size_t)(base + r) * D))[l] = acc0;
        if (base + r + 8 < N)
            ((float4*)(keys + (size_t)(base + r + 8) * D))[l] = acc1;
    }
}

// ---------------- fused edge pass ----------------
// half-wave (32 lanes) per edge: score = dot(vals, keys[idx])/sqrt(D);
// ex = exp(score) (no max subtraction: scores ~N(0,1), overflow impossible);
// atomicAdd ex*vals into agg (= d_out), ex into denom.
__global__ __launch_bounds__(256) void edge_kernel(
    const float* __restrict__ occ3, const int* __restrict__ idx3,
    const float* __restrict__ occ5, const int* __restrict__ idx5,
    const float* __restrict__ keys, float* __restrict__ agg,
    float* __restrict__ denom, int E3, int E)
{
    const int l = threadIdx.x & 31;
    const int sub = threadIdx.x >> 5;   // 0..7 edge slot in block
    long long e = (long long)blockIdx.x * 8 + sub;
    if (e >= E) return;

    const float* vrow;
    int n;
    if (e < E3) { vrow = occ3 + e * D;               n = idx3[e]; }
    else        { long long e5 = e - E3; vrow = occ5 + e5 * D; n = idx5[e5]; }

    float4 v = ((const float4*)vrow)[l];
    float4 k = ((const float4*)(keys + (size_t)n * D))[l];
    float s = v.x * k.x + v.y * k.y + v.z * k.z + v.w * k.w;
    s += __shfl_xor(s, 16); s += __shfl_xor(s, 8);
    s += __shfl_xor(s, 4);  s += __shfl_xor(s, 2); s += __shfl_xor(s, 1);

    float ex = __expf(s * 0.0883883476483184f);   // 1/sqrt(128)

    float* dst = agg + (size_t)n * D + l * 4;
    atomicAdd(dst + 0, ex * v.x);
    atomicAdd(dst + 1, ex * v.y);
    atomicAdd(dst + 2, ex * v.z);
    atomicAdd(dst + 3, ex * v.w);
    if (l == 0) atomicAdd(denom + n, ex);
}

// ---------------- gate ----------------
// aggn = agg/(denom+eps); z = sigmoid([prev;aggn] @ gate_W + gate_b);
// out = z*aggn + (1-z)*prev, written in place over agg (= d_out).
__global__ __launch_bounds__(256) void gate_kernel(
    const float* __restrict__ prev, const float* __restrict__ gate_W,
    const float* __restrict__ gate_b, const float* __restrict__ denom,
    float* __restrict__ out, int N)
{
    __shared__ float Wl[2 * D * D];   // 128 KB: gate_W[256][128]
    __shared__ float bl[D];
    __shared__ float pl[16][D];       // 8 KB prev rows
    __shared__ float al[16][D];       // 8 KB normalized agg rows

    for (int i = threadIdx.x; i < 2 * D * D / 4; i += 256)
        ((float4*)Wl)[i] = ((const float4*)gate_W)[i];
    if (threadIdx.x < D) bl[threadIdx.x] = gate_b[threadIdx.x];

    const int l = threadIdx.x & 31;
    const int r = threadIdx.x >> 5;
    const float4* W4 = (const float4*)Wl;

    for (int base = blockIdx.x * 16; base < N; base += gridDim.x * 16) {
        __syncthreads();
        int navail = N - base; if (navail > 16) navail = 16;
        for (int i = threadIdx.x; i < navail * (D / 4); i += 256) {
            int row = i >> 5;                       // i / (D/4)
            ((float4*)pl)[i] = ((const float4*)(prev + (size_t)base * D))[i];
            float inv = 1.0f / (denom[base + row] + EPSF);
            float4 a = ((const float4*)(out + (size_t)base * D))[i];
            a.x *= inv; a.y *= inv; a.z *= inv; a.w *= inv;
            ((float4*)al)[i] = a;
        }
        __syncthreads();

        float4 z0 = ((const float4*)bl)[l];
        float4 z1 = z0;
        #pragma unroll 4
        for (int d = 0; d < D; ++d) {
            float4 w = W4[d * 32 + l];
            float p0 = pl[r][d], p1 = pl[r + 8][d];
            z0.x = fmaf(p0, w.x, z0.x); z0.y = fmaf(p0, w.y, z0.y);
            z0.z = fmaf(p0, w.z, z0.z); z0.w = fmaf(p0, w.w, z0.w);
            z1.x = fmaf(p1, w.x, z1.x); z1.y = fmaf(p1, w.y, z1.y);
            z1.z = fmaf(p1, w.z, z1.z); z1.w = fmaf(p1, w.w, z1.w);
        }
        #pragma unroll 4
        for (int d = 0; d < D; ++d) {
            float4 w = W4[(D + d) * 32 + l];
            float a0 = al[r][d], a1 = al[r + 8][d];
            z0.x = fmaf(a0, w.x, z0.x); z0.y = fmaf(a0, w.y, z0.y);
            z0.z = fmaf(a0, w.z, z0.z); z0.w = fmaf(a0, w.w, z0.w);
            z1.x = fmaf(a1, w.x, z1.x); z1.y = fmaf(a1, w.y, z1.y);
            z1.z = fmaf(a1, w.z, z1.z); z1.w = fmaf(a1, w.w, z1.w);
        }

        float4 zs0, zs1;
        zs0.x = 1.0f / (1.0f + __expf(-z0.x)); zs0.y = 1.0f / (1.0f + __expf(-z0.y));
        zs0.z = 1.0f / (1.0f + __expf(-z0.z)); zs0.w = 1.0f / (1.0f + __expf(-z0.w));
        zs1.x = 1.0f / (1.0f + __expf(-z1.x)); zs1.y = 1.0f / (1.0f + __expf(-z1.y));
        zs1.z = 1.0f / (1.0f + __expf(-z1.z)); zs1.w = 1.0f / (1.0f + __expf(-z1.w));

        if (base + r < N) {
            float4 a = ((const float4*)al)[r * 32 + l];
            float4 p = ((const float4*)pl)[r * 32 + l];
            float4 o;
            o.x = fmaf(zs0.x, a.x - p.x, p.x);
            o.y = fmaf(zs0.y, a.y - p.y, p.y);
            o.z = fmaf(zs0.z, a.z - p.z, p.z);
            o.w = fmaf(zs0.w, a.w - p.w, p.w);
            ((float4*)(out + (size_t)(base + r) * D))[l] = o;
        }
        if (base + r + 8 < N) {
            float4 a = ((const float4*)al)[(r + 8) * 32 + l];
            float4 p = ((const float4*)pl)[(r + 8) * 32 + l];
            float4 o;
            o.x = fmaf(zs1.x, a.x - p.x, p.x);
            o.y = fmaf(zs1.y, a.y - p.y, p.y);
            o.z = fmaf(zs1.z, a.z - p.z, p.z);
            o.w = fmaf(zs1.w, a.w - p.w, p.w);
            ((float4*)(out + (size_t)(base + r + 8) * D))[l] = o;
        }
    }
}

extern "C" void kernel_launch(void* const* d_in, const int* in_sizes, int n_in,
                              void* d_out, int out_size, void* d_ws, size_t ws_size,
                              hipStream_t stream)
{
    const float* occ3   = (const float*)d_in[0];
    const int*   idx3   = (const int*)d_in[1];     // harness pushes integers as int32
    const float* occ5   = (const float*)d_in[2];
    const int*   idx5   = (const int*)d_in[3];
    const float* prev   = (const float*)d_in[4];
    const float* attn_W = (const float*)d_in[5];
    const float* attn_b = (const float*)d_in[6];
    const float* gate_W = (const float*)d_in[7];
    const float* gate_b = (const float*)d_in[8];

    const int N  = in_sizes[4] / D;
    const int E3 = in_sizes[1];
    const int E5 = in_sizes[3];
    const int E  = E3 + E5;

    float* keys  = (float*)d_ws;                  // N*D floats
    float* denom = keys + (size_t)N * D;          // N floats
    float* agg   = (float*)d_out;                 // accumulate here, overwritten by gate

    hipMemsetAsync(d_out, 0, (size_t)out_size * sizeof(float), stream);
    hipMemsetAsync(denom, 0, (size_t)N * sizeof(float), stream);

    keys_kernel<<<2048, 256, 0, stream>>>(prev, attn_W, attn_b, keys, N);

    int eblocks = (E + 7) / 8;
    edge_kernel<<<eblocks, 256, 0, stream>>>(occ3, idx3, occ5, idx5, keys, agg, denom, E3, E);

    gate_kernel<<<1024, 256, 0, stream>>>(prev, gate_W, gate_b, denom, agg, N);
}

// Round 4
// 1399.022 us; speedup vs baseline: 2.8144x; 2.8144x over previous
//
#include <hip/hip_runtime.h>
#include <math.h>

#define D 128
#define EPSF 1e-9f

static __device__ __forceinline__ unsigned short f2bf(float f) {
    union { float f; unsigned int u; } c; c.f = f;
    unsigned int u = c.u + 0x7fffu + ((c.u >> 16) & 1u);
    return (unsigned short)(u >> 16);
}
static __device__ __forceinline__ float bf2f(unsigned short h) {
    union { unsigned int u; float f; } c; c.u = ((unsigned int)h) << 16;
    return c.f;
}

// ---------------- keys = bf16( prev @ attn_W + attn_b )  [N,128] ----------------
__global__ __launch_bounds__(256, 2) void keys_kernel(
    const float* __restrict__ prev, const float* __restrict__ attn_W,
    const float* __restrict__ attn_b, unsigned short* __restrict__ keysb, int N)
{
    __shared__ float Wl[D * D];       // 64 KB
    __shared__ float bl[D];
    __shared__ float rows[16][D];     // 8 KB

    for (int i = threadIdx.x; i < D * D / 4; i += 256)
        ((float4*)Wl)[i] = ((const float4*)attn_W)[i];
    if (threadIdx.x < D) bl[threadIdx.x] = attn_b[threadIdx.x];

    const int l = threadIdx.x & 31;
    const int r = threadIdx.x >> 5;
    const float4* W4 = (const float4*)Wl;

    for (int base = blockIdx.x * 16; base < N; base += gridDim.x * 16) {
        __syncthreads();
        int navail = N - base; if (navail > 16) navail = 16;
        for (int i = threadIdx.x; i < navail * (D / 4); i += 256)
            ((float4*)rows)[i] = ((const float4*)(prev + (size_t)base * D))[i];
        __syncthreads();

        float4 acc0 = ((const float4*)bl)[l];
        float4 acc1 = acc0;
        #pragma unroll 8
        for (int d = 0; d < D; ++d) {
            float4 w = W4[d * 32 + l];
            float p0 = rows[r][d];
            float p1 = rows[r + 8][d];
            acc0.x = fmaf(p0, w.x, acc0.x); acc0.y = fmaf(p0, w.y, acc0.y);
            acc0.z = fmaf(p0, w.z, acc0.z); acc0.w = fmaf(p0, w.w, acc0.w);
            acc1.x = fmaf(p1, w.x, acc1.x); acc1.y = fmaf(p1, w.y, acc1.y);
            acc1.z = fmaf(p1, w.z, acc1.z); acc1.w = fmaf(p1, w.w, acc1.w);
        }
        if (base + r < N) {
            ushort4 o; o.x = f2bf(acc0.x); o.y = f2bf(acc0.y);
            o.z = f2bf(acc0.z); o.w = f2bf(acc0.w);
            ((ushort4*)(keysb + (size_t)(base + r) * D))[l] = o;
        }
        if (base + r + 8 < N) {
            ushort4 o; o.x = f2bf(acc1.x); o.y = f2bf(acc1.y);
            o.z = f2bf(acc1.z); o.w = f2bf(acc1.w);
            ((ushort4*)(keysb + (size_t)(base + r + 8) * D))[l] = o;
        }
    }
}

// ---------------- CSR build ----------------
__global__ __launch_bounds__(256) void hist_kernel(
    const int* __restrict__ idx3, const int* __restrict__ idx5,
    int* __restrict__ cnt, int E3, int E)
{
    int e = blockIdx.x * 256 + threadIdx.x;
    if (e >= E) return;
    int n = (e < E3) ? idx3[e] : idx5[e - E3];
    atomicAdd(&cnt[n], 1);
}

// block scans CHUNK=1024 counts -> local exclusive scan + chunk total
__global__ __launch_bounds__(256) void scan1_kernel(
    const int* __restrict__ cnt, int* __restrict__ row_start,
    int* __restrict__ bsum, int N)
{
    __shared__ int tsum[256];
    const int t = threadIdx.x;
    const int base = blockIdx.x * 1024;
    const int i0 = base + t * 4;
    int v0 = 0, v1 = 0, v2 = 0, v3 = 0;
    if (i0 + 0 < N) v0 = cnt[i0 + 0];
    if (i0 + 1 < N) v1 = cnt[i0 + 1];
    if (i0 + 2 < N) v2 = cnt[i0 + 2];
    if (i0 + 3 < N) v3 = cnt[i0 + 3];
    int s = v0 + v1 + v2 + v3;
    tsum[t] = s;
    __syncthreads();
    int val = s;
    for (int off = 1; off < 256; off <<= 1) {
        int tmp = (t >= off) ? tsum[t - off] : 0;
        __syncthreads();
        val += tmp; tsum[t] = val;
        __syncthreads();
    }
    int excl = val - s;                 // exclusive prefix within chunk
    if (i0 + 0 < N) row_start[i0 + 0] = excl;            excl += v0;
    if (i0 + 1 < N) row_start[i0 + 1] = excl;            excl += v1;
    if (i0 + 2 < N) row_start[i0 + 2] = excl;            excl += v2;
    if (i0 + 3 < N) row_start[i0 + 3] = excl;
    if (t == 255) bsum[blockIdx.x] = val;                // chunk total
}

__global__ __launch_bounds__(1024) void scan2_kernel(int* __restrict__ bsum, int nb)
{
    __shared__ int sh[1024];
    const int t = threadIdx.x;
    int v = (t < nb) ? bsum[t] : 0;
    sh[t] = v;
    __syncthreads();
    int val = v;
    for (int off = 1; off < 1024; off <<= 1) {
        int tmp = (t >= off) ? sh[t - off] : 0;
        __syncthreads();
        val += tmp; sh[t] = val;
        __syncthreads();
    }
    if (t < nb) bsum[t] = val - v;      // exclusive scan of chunk totals
}

__global__ __launch_bounds__(256) void scan3_kernel(
    int* __restrict__ row_start, const int* __restrict__ bsum, int N, int E)
{
    int i = blockIdx.x * 256 + threadIdx.x;
    if (i < N)       row_start[i] += bsum[i >> 10];
    else if (i == N) row_start[N] = E;
}

__global__ __launch_bounds__(256) void scatter_kernel(
    const int* __restrict__ idx3, const int* __restrict__ idx5,
    const int* __restrict__ row_start, int* __restrict__ cursor,
    int* __restrict__ edge_ids, int E3, int E)
{
    int e = blockIdx.x * 256 + threadIdx.x;
    if (e >= E) return;
    int n = (e < E3) ? idx3[e] : idx5[e - E3];
    int p = row_start[n] + atomicAdd(&cursor[n], 1);
    edge_ids[p] = e;
}

// ---------------- per-node attention aggregate (no atomics) ----------------
// one 64-lane wave per node; lane owns dims 2l, 2l+1 (float2).
__global__ __launch_bounds__(256) void agg_kernel(
    const float* __restrict__ occ3, const float* __restrict__ occ5,
    const unsigned short* __restrict__ keysb,
    const int* __restrict__ row_start, const int* __restrict__ edge_ids,
    float* __restrict__ out, int E3, int N)
{
    const int lane = threadIdx.x & 63;
    const int wid  = threadIdx.x >> 6;
    const int n = blockIdx.x * 4 + wid;
    if (n >= N) return;

    unsigned int kp = ((const unsigned int*)keysb)[(size_t)n * (D / 2) + lane];
    float2 k;
    k.x = bf2f((unsigned short)(kp & 0xffffu));
    k.y = bf2f((unsigned short)(kp >> 16));

    const int rs = row_start[n];
    const int re = row_start[n + 1];

    float2 acc = {0.f, 0.f};
    float den = 0.f;
    for (int i = rs; i < re; ++i) {
        int e = edge_ids[i];
        const float2* vp = (e < E3)
            ? (const float2*)(occ3 + (size_t)e * D)
            : (const float2*)(occ5 + (size_t)(e - E3) * D);
        float2 v = vp[lane];
        float s = v.x * k.x + v.y * k.y;
        s += __shfl_xor(s, 32); s += __shfl_xor(s, 16); s += __shfl_xor(s, 8);
        s += __shfl_xor(s, 4);  s += __shfl_xor(s, 2);  s += __shfl_xor(s, 1);
        float ex = __expf(s * 0.0883883476483184f);   // 1/sqrt(128)
        den += ex;
        acc.x = fmaf(ex, v.x, acc.x);
        acc.y = fmaf(ex, v.y, acc.y);
    }
    float inv = 1.0f / (den + EPSF);
    float2 o = {acc.x * inv, acc.y * inv};
    ((float2*)(out + (size_t)n * D))[lane] = o;
}

// ---------------- gate ----------------
// reads pre-normalized aggn from out; z = sigmoid([prev;aggn] @ gate_W + gate_b);
// out = z*aggn + (1-z)*prev, in place.
__global__ __launch_bounds__(256) void gate_kernel(
    const float* __restrict__ prev, const float* __restrict__ gate_W,
    const float* __restrict__ gate_b, float* __restrict__ out, int N)
{
    __shared__ float Wl[2 * D * D];   // 128 KB
    __shared__ float bl[D];
    __shared__ float pl[16][D];       // 8 KB
    __shared__ float al[16][D];       // 8 KB

    for (int i = threadIdx.x; i < 2 * D * D / 4; i += 256)
        ((float4*)Wl)[i] = ((const float4*)gate_W)[i];
    if (threadIdx.x < D) bl[threadIdx.x] = gate_b[threadIdx.x];

    const int l = threadIdx.x & 31;
    const int r = threadIdx.x >> 5;
    const float4* W4 = (const float4*)Wl;

    for (int base = blockIdx.x * 16; base < N; base += gridDim.x * 16) {
        __syncthreads();
        int navail = N - base; if (navail > 16) navail = 16;
        for (int i = threadIdx.x; i < navail * (D / 4); i += 256) {
            ((float4*)pl)[i] = ((const float4*)(prev + (size_t)base * D))[i];
            ((float4*)al)[i] = ((const float4*)(out  + (size_t)base * D))[i];
        }
        __syncthreads();

        float4 z0 = ((const float4*)bl)[l];
        float4 z1 = z0;
        #pragma unroll 4
        for (int d = 0; d < D; ++d) {
            float4 w = W4[d * 32 + l];
            float p0 = pl[r][d], p1 = pl[r + 8][d];
            z0.x = fmaf(p0, w.x, z0.x); z0.y = fmaf(p0, w.y, z0.y);
            z0.z = fmaf(p0, w.z, z0.z); z0.w = fmaf(p0, w.w, z0.w);
            z1.x = fmaf(p1, w.x, z1.x); z1.y = fmaf(p1, w.y, z1.y);
            z1.z = fmaf(p1, w.z, z1.z); z1.w = fmaf(p1, w.w, z1.w);
        }
        #pragma unroll 4
        for (int d = 0; d < D; ++d) {
            float4 w = W4[(D + d) * 32 + l];
            float a0 = al[r][d], a1 = al[r + 8][d];
            z0.x = fmaf(a0, w.x, z0.x); z0.y = fmaf(a0, w.y, z0.y);
            z0.z = fmaf(a0, w.z, z0.z); z0.w = fmaf(a0, w.w, z0.w);
            z1.x = fmaf(a1, w.x, z1.x); z1.y = fmaf(a1, w.y, z1.y);
            z1.z = fmaf(a1, w.z, z1.z); z1.w = fmaf(a1, w.w, z1.w);
        }

        float4 zs0, zs1;
        zs0.x = 1.0f / (1.0f + __expf(-z0.x)); zs0.y = 1.0f / (1.0f + __expf(-z0.y));
        zs0.z = 1.0f / (1.0f + __expf(-z0.z)); zs0.w = 1.0f / (1.0f + __expf(-z0.w));
        zs1.x = 1.0f / (1.0f + __expf(-z1.x)); zs1.y = 1.0f / (1.0f + __expf(-z1.y));
        zs1.z = 1.0f / (1.0f + __expf(-z1.z)); zs1.w = 1.0f / (1.0f + __expf(-z1.w));

        if (base + r < N) {
            float4 a = ((const float4*)al)[r * 32 + l];
            float4 p = ((const float4*)pl)[r * 32 + l];
            float4 o;
            o.x = fmaf(zs0.x, a.x - p.x, p.x);
            o.y = fmaf(zs0.y, a.y - p.y, p.y);
            o.z = fmaf(zs0.z, a.z - p.z, p.z);
            o.w = fmaf(zs0.w, a.w - p.w, p.w);
            ((float4*)(out + (size_t)(base + r) * D))[l] = o;
        }
        if (base + r + 8 < N) {
            float4 a = ((const float4*)al)[(r + 8) * 32 + l];
            float4 p = ((const float4*)pl)[(r + 8) * 32 + l];
            float4 o;
            o.x = fmaf(zs1.x, a.x - p.x, p.x);
            o.y = fmaf(zs1.y, a.y - p.y, p.y);
            o.z = fmaf(zs1.z, a.z - p.z, p.z);
            o.w = fmaf(zs1.w, a.w - p.w, p.w);
            ((float4*)(out + (size_t)(base + r + 8) * D))[l] = o;
        }
    }
}

extern "C" void kernel_launch(void* const* d_in, const int* in_sizes, int n_in,
                              void* d_out, int out_size, void* d_ws, size_t ws_size,
                              hipStream_t stream)
{
    const float* occ3   = (const float*)d_in[0];
    const int*   idx3   = (const int*)d_in[1];     // harness pushes integers as int32
    const float* occ5   = (const float*)d_in[2];
    const int*   idx5   = (const int*)d_in[3];
    const float* prev   = (const float*)d_in[4];
    const float* attn_W = (const float*)d_in[5];
    const float* attn_b = (const float*)d_in[6];
    const float* gate_W = (const float*)d_in[7];
    const float* gate_b = (const float*)d_in[8];

    const int N  = in_sizes[4] / D;
    const int E3 = in_sizes[1];
    const int E5 = in_sizes[3];
    const int E  = E3 + E5;

    // ws layout: keys(bf16, N*D) | row_start(N+1) | cnt(N) | cursor(N) | bsum(1025) | edge_ids(E)
    unsigned short* keysb = (unsigned short*)d_ws;
    int* row_start = (int*)(keysb + (size_t)N * D);
    int* cnt       = row_start + (N + 1);
    int* cursor    = cnt + N;
    int* bsum      = cursor + N;
    int* edge_ids  = bsum + 1025;

    float* out = (float*)d_out;

    hipMemsetAsync(cnt,    0, (size_t)N * sizeof(int), stream);
    hipMemsetAsync(cursor, 0, (size_t)N * sizeof(int), stream);

    const int nb = (N + 1023) / 1024;            // scan chunks (<=1024 assumed)
    hist_kernel   <<<(E + 255) / 256, 256, 0, stream>>>(idx3, idx5, cnt, E3, E);
    scan1_kernel  <<<nb, 256, 0, stream>>>(cnt, row_start, bsum, N);
    scan2_kernel  <<<1, 1024, 0, stream>>>(bsum, nb);
    scan3_kernel  <<<(N + 256) / 256, 256, 0, stream>>>(row_start, bsum, N, E);
    scatter_kernel<<<(E + 255) / 256, 256, 0, stream>>>(idx3, idx5, row_start, cursor, edge_ids, E3, E);

    keys_kernel<<<2048, 256, 0, stream>>>(prev, attn_W, attn_b, keysb, N);

    agg_kernel<<<(N + 3) / 4, 256, 0, stream>>>(occ3, occ5, keysb, row_start, edge_ids, out, E3, N);

    gate_kernel<<<1024, 256, 0, stream>>>(prev, gate_W, gate_b, out, N);
}

// Round 5
// 977.238 us; speedup vs baseline: 4.0291x; 1.4316x over previous
//
#include <hip/hip_runtime.h>
#include <math.h>

#define D 128
#define EPSF 1e-9f

typedef __bf16 bf16x8 __attribute__((ext_vector_type(8)));
typedef float  f32x4  __attribute__((ext_vector_type(4)));

static __device__ __forceinline__ float bf2f(unsigned short h) {
    union { unsigned int u; float f; } c; c.u = ((unsigned int)h) << 16;
    return c.f;
}

// ---------------- W transpose to bf16 (tiny, once) ----------------
// wta[n][k] = attn_W[k][n]  (128x128), wtg[n][k] = gate_W[k][n]  (128 rows x 256 k)
__global__ __launch_bounds__(256) void transpose_w_kernel(
    const float* __restrict__ attn_W, const float* __restrict__ gate_W,
    __bf16* __restrict__ wta, __bf16* __restrict__ wtg)
{
    int i = blockIdx.x * 256 + threadIdx.x;
    if (i < 128 * 128) {
        int k = i >> 7, n = i & 127;
        wta[n * 128 + k] = (__bf16)attn_W[i];
    }
    if (i < 256 * 128) {
        int k = i >> 7, n = i & 127;
        wtg[n * 256 + k] = (__bf16)gate_W[i];
    }
}

// ---------------- keys = bf16( prev @ attn_W + attn_b ), MFMA ----------------
// wave = 16 rows x 128 cols; A from global fp32 (cvt), B from global bf16 W^T (L2).
__global__ __launch_bounds__(256) void keys_mfma_kernel(
    const float* __restrict__ prev, const __bf16* __restrict__ wta,
    const float* __restrict__ attn_b, unsigned short* __restrict__ keysb, int N)
{
    const int lane = threadIdx.x & 63;
    const int wid  = threadIdx.x >> 6;
    const int m0 = (blockIdx.x * 4 + wid) * 16;
    if (m0 >= N) return;
    const int lm = lane & 15;
    const int lg = lane >> 4;

    int arow = m0 + lm; if (arow >= N) arow = m0;
    const float* ap = prev + (size_t)arow * D + lg * 8;

    f32x4 acc[8] = {};
    #pragma unroll
    for (int kk = 0; kk < 4; ++kk) {
        float4 a0 = *(const float4*)(ap + kk * 32);
        float4 a1 = *(const float4*)(ap + kk * 32 + 4);
        bf16x8 af;
        af[0] = (__bf16)a0.x; af[1] = (__bf16)a0.y; af[2] = (__bf16)a0.z; af[3] = (__bf16)a0.w;
        af[4] = (__bf16)a1.x; af[5] = (__bf16)a1.y; af[6] = (__bf16)a1.z; af[7] = (__bf16)a1.w;
        const int k0 = kk * 32;
        #pragma unroll
        for (int t = 0; t < 8; ++t) {
            bf16x8 bf_ = *(const bf16x8*)(wta + (size_t)(t * 16 + lm) * 128 + k0 + lg * 8);
            acc[t] = __builtin_amdgcn_mfma_f32_16x16x32_bf16(af, bf_, acc[t], 0, 0, 0);
        }
    }
    __bf16* kb = (__bf16*)keysb;
    #pragma unroll
    for (int t = 0; t < 8; ++t) {
        float bcol = attn_b[t * 16 + lm];
        #pragma unroll
        for (int r = 0; r < 4; ++r) {
            int row = m0 + lg * 4 + r;
            if (row < N)
                kb[(size_t)row * D + t * 16 + lm] = (__bf16)(acc[t][r] + bcol);
        }
    }
}

// ---------------- CSR build ----------------
__global__ __launch_bounds__(256) void hist_kernel(
    const int* __restrict__ idx3, const int* __restrict__ idx5,
    int* __restrict__ cnt, int E3, int E)
{
    int e = blockIdx.x * 256 + threadIdx.x;
    if (e >= E) return;
    int n = (e < E3) ? idx3[e] : idx5[e - E3];
    atomicAdd(&cnt[n], 1);
}

__global__ __launch_bounds__(256) void scan1_kernel(
    const int* __restrict__ cnt, int* __restrict__ row_start,
    int* __restrict__ bsum, int N)
{
    __shared__ int tsum[256];
    const int t = threadIdx.x;
    const int base = blockIdx.x * 1024;
    const int i0 = base + t * 4;
    int v0 = 0, v1 = 0, v2 = 0, v3 = 0;
    if (i0 + 0 < N) v0 = cnt[i0 + 0];
    if (i0 + 1 < N) v1 = cnt[i0 + 1];
    if (i0 + 2 < N) v2 = cnt[i0 + 2];
    if (i0 + 3 < N) v3 = cnt[i0 + 3];
    int s = v0 + v1 + v2 + v3;
    tsum[t] = s;
    __syncthreads();
    int val = s;
    for (int off = 1; off < 256; off <<= 1) {
        int tmp = (t >= off) ? tsum[t - off] : 0;
        __syncthreads();
        val += tmp; tsum[t] = val;
        __syncthreads();
    }
    int excl = val - s;
    if (i0 + 0 < N) row_start[i0 + 0] = excl;            excl += v0;
    if (i0 + 1 < N) row_start[i0 + 1] = excl;            excl += v1;
    if (i0 + 2 < N) row_start[i0 + 2] = excl;            excl += v2;
    if (i0 + 3 < N) row_start[i0 + 3] = excl;
    if (t == 255) bsum[blockIdx.x] = val;
}

__global__ __launch_bounds__(1024) void scan2_kernel(int* __restrict__ bsum, int nb)
{
    __shared__ int sh[1024];
    const int t = threadIdx.x;
    int v = (t < nb) ? bsum[t] : 0;
    sh[t] = v;
    __syncthreads();
    int val = v;
    for (int off = 1; off < 1024; off <<= 1) {
        int tmp = (t >= off) ? sh[t - off] : 0;
        __syncthreads();
        val += tmp; sh[t] = val;
        __syncthreads();
    }
    if (t < nb) bsum[t] = val - v;
}

__global__ __launch_bounds__(256) void scan3_kernel(
    int* __restrict__ row_start, const int* __restrict__ bsum, int N, int E)
{
    int i = blockIdx.x * 256 + threadIdx.x;
    if (i < N)       row_start[i] += bsum[i >> 10];
    else if (i == N) row_start[N] = E;
}

__global__ __launch_bounds__(256) void scatter_kernel(
    const int* __restrict__ idx3, const int* __restrict__ idx5,
    const int* __restrict__ row_start, int* __restrict__ cursor,
    int* __restrict__ edge_ids, int E3, int E)
{
    int e = blockIdx.x * 256 + threadIdx.x;
    if (e >= E) return;
    int n = (e < E3) ? idx3[e] : idx5[e - E3];
    int p = row_start[n] + atomicAdd(&cursor[n], 1);
    edge_ids[p] = e;
}

// ---------------- per-node attention aggregate (no atomics) ----------------
__global__ __launch_bounds__(256) void agg_kernel(
    const float* __restrict__ occ3, const float* __restrict__ occ5,
    const unsigned short* __restrict__ keysb,
    const int* __restrict__ row_start, const int* __restrict__ edge_ids,
    float* __restrict__ out, int E3, int N)
{
    const int lane = threadIdx.x & 63;
    const int wid  = threadIdx.x >> 6;
    const int n = blockIdx.x * 4 + wid;
    if (n >= N) return;

    unsigned int kp = ((const unsigned int*)keysb)[(size_t)n * (D / 2) + lane];
    float2 k;
    k.x = bf2f((unsigned short)(kp & 0xffffu));
    k.y = bf2f((unsigned short)(kp >> 16));

    const int rs = row_start[n];
    const int re = row_start[n + 1];

    float2 acc = {0.f, 0.f};
    float den = 0.f;
    for (int i = rs; i < re; ++i) {
        int e = edge_ids[i];
        const float2* vp = (e < E3)
            ? (const float2*)(occ3 + (size_t)e * D)
            : (const float2*)(occ5 + (size_t)(e - E3) * D);
        float2 v = vp[lane];
        float s = v.x * k.x + v.y * k.y;
        s += __shfl_xor(s, 32); s += __shfl_xor(s, 16); s += __shfl_xor(s, 8);
        s += __shfl_xor(s, 4);  s += __shfl_xor(s, 2);  s += __shfl_xor(s, 1);
        float ex = __expf(s * 0.0883883476483184f);   // 1/sqrt(128)
        den += ex;
        acc.x = fmaf(ex, v.x, acc.x);
        acc.y = fmaf(ex, v.y, acc.y);
    }
    float inv = 1.0f / (den + EPSF);
    float2 o = {acc.x * inv, acc.y * inv};
    ((float2*)(out + (size_t)n * D))[lane] = o;
}

// ---------------- gate via MFMA ----------------
// C = [prev | aggn] @ gate_W; z = sigmoid(C + b); out = z*aggn + (1-z)*prev.
// aggn lives in `out`; each wave owns rows [m0, m0+16) exclusively (read then write).
__global__ __launch_bounds__(256) void gate_mfma_kernel(
    const float* __restrict__ prev, const __bf16* __restrict__ wtg,
    const float* __restrict__ gate_b, float* __restrict__ out, int N)
{
    const int lane = threadIdx.x & 63;
    const int wid  = threadIdx.x >> 6;
    const int m0 = (blockIdx.x * 4 + wid) * 16;
    if (m0 >= N) return;
    const int lm = lane & 15;
    const int lg = lane >> 4;

    int arow = m0 + lm; if (arow >= N) arow = m0;   // clamp inside own tile (no cross-block race)
    const float* aprev = prev + (size_t)arow * D + lg * 8;
    const float* aagg  = out  + (size_t)arow * D + lg * 8;

    f32x4 acc[8] = {};
    #pragma unroll
    for (int kk = 0; kk < 8; ++kk) {
        const float* src = (kk < 4) ? (aprev + kk * 32) : (aagg + (kk - 4) * 32);
        float4 a0 = *(const float4*)(src);
        float4 a1 = *(const float4*)(src + 4);
        bf16x8 af;
        af[0] = (__bf16)a0.x; af[1] = (__bf16)a0.y; af[2] = (__bf16)a0.z; af[3] = (__bf16)a0.w;
        af[4] = (__bf16)a1.x; af[5] = (__bf16)a1.y; af[6] = (__bf16)a1.z; af[7] = (__bf16)a1.w;
        const int k0 = kk * 32;
        #pragma unroll
        for (int t = 0; t < 8; ++t) {
            bf16x8 bf_ = *(const bf16x8*)(wtg + (size_t)(t * 16 + lm) * 256 + k0 + lg * 8);
            acc[t] = __builtin_amdgcn_mfma_f32_16x16x32_bf16(af, bf_, acc[t], 0, 0, 0);
        }
    }

    #pragma unroll
    for (int t = 0; t < 8; ++t) {
        float bcol = gate_b[t * 16 + lm];
        #pragma unroll
        for (int r = 0; r < 4; ++r) {
            int row = m0 + lg * 4 + r;
            if (row < N) {
                size_t off = (size_t)row * D + t * 16 + lm;
                float c = acc[t][r] + bcol;
                float z = 1.0f / (1.0f + __expf(-c));
                float a = out[off];
                float p = prev[off];
                out[off] = fmaf(z, a - p, p);
            }
        }
    }
}

extern "C" void kernel_launch(void* const* d_in, const int* in_sizes, int n_in,
                              void* d_out, int out_size, void* d_ws, size_t ws_size,
                              hipStream_t stream)
{
    const float* occ3   = (const float*)d_in[0];
    const int*   idx3   = (const int*)d_in[1];     // harness pushes integers as int32
    const float* occ5   = (const float*)d_in[2];
    const int*   idx5   = (const int*)d_in[3];
    const float* prev   = (const float*)d_in[4];
    const float* attn_W = (const float*)d_in[5];
    const float* attn_b = (const float*)d_in[6];
    const float* gate_W = (const float*)d_in[7];
    const float* gate_b = (const float*)d_in[8];

    const int N  = in_sizes[4] / D;
    const int E3 = in_sizes[1];
    const int E5 = in_sizes[3];
    const int E  = E3 + E5;

    // ws: keysb(bf16 N*D) | row_start(N+1) | cnt(N) | cursor(N) | bsum(1025) | edge_ids(E) | wta(16K us) | wtg(32K us)
    unsigned short* keysb = (unsigned short*)d_ws;
    int* row_start = (int*)(keysb + (size_t)N * D);
    int* cnt       = row_start + (N + 1);
    int* cursor    = cnt + N;
    int* bsum      = cursor + N;
    int* edge_ids  = bsum + 1025;
    __bf16* wta    = (__bf16*)(edge_ids + E);
    __bf16* wtg    = wta + 128 * 128;

    float* out = (float*)d_out;

    hipMemsetAsync(cnt,    0, (size_t)N * sizeof(int), stream);
    hipMemsetAsync(cursor, 0, (size_t)N * sizeof(int), stream);

    transpose_w_kernel<<<128, 256, 0, stream>>>(attn_W, gate_W, wta, wtg);

    const int nb = (N + 1023) / 1024;
    hist_kernel   <<<(E + 255) / 256, 256, 0, stream>>>(idx3, idx5, cnt, E3, E);
    scan1_kernel  <<<nb, 256, 0, stream>>>(cnt, row_start, bsum, N);
    scan2_kernel  <<<1, 1024, 0, stream>>>(bsum, nb);
    scan3_kernel  <<<(N + 256) / 256, 256, 0, stream>>>(row_start, bsum, N, E);
    scatter_kernel<<<(E + 255) / 256, 256, 0, stream>>>(idx3, idx5, row_start, cursor, edge_ids, E3, E);

    keys_mfma_kernel<<<(N + 63) / 64, 256, 0, stream>>>(prev, wta, attn_b, keysb, N);

    agg_kernel<<<(N + 3) / 4, 256, 0, stream>>>(occ3, occ5, keysb, row_start, edge_ids, out, E3, N);

    gate_mfma_kernel<<<(N + 63) / 64, 256, 0, stream>>>(prev, wtg, gate_b, out, N);
}

// Round 7
// 825.046 us; speedup vs baseline: 4.7724x; 1.1845x over previous
//
#include <hip/hip_runtime.h>
#include <math.h>

#define D 128
#define EPSF 1e-9f

typedef __bf16 bf16x8 __attribute__((ext_vector_type(8)));
typedef float  f32x4  __attribute__((ext_vector_type(4)));
typedef float  f32x2  __attribute__((ext_vector_type(2)));

static __device__ __forceinline__ float bf2f(unsigned short h) {
    union { unsigned int u; float f; } c; c.u = ((unsigned int)h) << 16;
    return c.f;
}

// ---------------- W transpose to bf16 (tiny, once) ----------------
__global__ __launch_bounds__(256) void transpose_w_kernel(
    const float* __restrict__ attn_W, const float* __restrict__ gate_W,
    __bf16* __restrict__ wta, __bf16* __restrict__ wtg)
{
    int i = blockIdx.x * 256 + threadIdx.x;
    if (i < 128 * 128) {
        int k = i >> 7, n = i & 127;
        wta[n * 128 + k] = (__bf16)attn_W[i];
    }
    if (i < 256 * 128) {
        int k = i >> 7, n = i & 127;
        wtg[n * 256 + k] = (__bf16)gate_W[i];
    }
}

// ---------------- keys = bf16( prev @ attn_W + attn_b ), MFMA ----------------
__global__ __launch_bounds__(256) void keys_mfma_kernel(
    const float* __restrict__ prev, const __bf16* __restrict__ wta,
    const float* __restrict__ attn_b, unsigned short* __restrict__ keysb, int N)
{
    const int lane = threadIdx.x & 63;
    const int wid  = threadIdx.x >> 6;
    const int m0 = (blockIdx.x * 4 + wid) * 16;
    if (m0 >= N) return;
    const int lm = lane & 15;
    const int lg = lane >> 4;

    int arow = m0 + lm; if (arow >= N) arow = m0;
    const float* ap = prev + (size_t)arow * D + lg * 8;

    f32x4 acc[8] = {};
    #pragma unroll
    for (int kk = 0; kk < 4; ++kk) {
        float4 a0 = *(const float4*)(ap + kk * 32);
        float4 a1 = *(const float4*)(ap + kk * 32 + 4);
        bf16x8 af;
        af[0] = (__bf16)a0.x; af[1] = (__bf16)a0.y; af[2] = (__bf16)a0.z; af[3] = (__bf16)a0.w;
        af[4] = (__bf16)a1.x; af[5] = (__bf16)a1.y; af[6] = (__bf16)a1.z; af[7] = (__bf16)a1.w;
        const int k0 = kk * 32;
        #pragma unroll
        for (int t = 0; t < 8; ++t) {
            bf16x8 bf_ = *(const bf16x8*)(wta + (size_t)(t * 16 + lm) * 128 + k0 + lg * 8);
            acc[t] = __builtin_amdgcn_mfma_f32_16x16x32_bf16(af, bf_, acc[t], 0, 0, 0);
        }
    }
    __bf16* kb = (__bf16*)keysb;
    #pragma unroll
    for (int t = 0; t < 8; ++t) {
        float bcol = attn_b[t * 16 + lm];
        #pragma unroll
        for (int r = 0; r < 4; ++r) {
            int row = m0 + lg * 4 + r;
            if (row < N)
                kb[(size_t)row * D + t * 16 + lm] = (__bf16)(acc[t][r] + bcol);
        }
    }
}

// ---------------- CSR build ----------------
__global__ __launch_bounds__(256) void hist_kernel(
    const int* __restrict__ idx3, const int* __restrict__ idx5,
    int* __restrict__ cnt, int E3, int E)
{
    int e = blockIdx.x * 256 + threadIdx.x;
    if (e >= E) return;
    int n = (e < E3) ? idx3[e] : idx5[e - E3];
    atomicAdd(&cnt[n], 1);
}

__global__ __launch_bounds__(256) void scan1_kernel(
    const int* __restrict__ cnt, int* __restrict__ row_start,
    int* __restrict__ bsum, int N)
{
    __shared__ int tsum[256];
    const int t = threadIdx.x;
    const int base = blockIdx.x * 1024;
    const int i0 = base + t * 4;
    int v0 = 0, v1 = 0, v2 = 0, v3 = 0;
    if (i0 + 0 < N) v0 = cnt[i0 + 0];
    if (i0 + 1 < N) v1 = cnt[i0 + 1];
    if (i0 + 2 < N) v2 = cnt[i0 + 2];
    if (i0 + 3 < N) v3 = cnt[i0 + 3];
    int s = v0 + v1 + v2 + v3;
    tsum[t] = s;
    __syncthreads();
    int val = s;
    for (int off = 1; off < 256; off <<= 1) {
        int tmp = (t >= off) ? tsum[t - off] : 0;
        __syncthreads();
        val += tmp; tsum[t] = val;
        __syncthreads();
    }
    int excl = val - s;
    if (i0 + 0 < N) row_start[i0 + 0] = excl;            excl += v0;
    if (i0 + 1 < N) row_start[i0 + 1] = excl;            excl += v1;
    if (i0 + 2 < N) row_start[i0 + 2] = excl;            excl += v2;
    if (i0 + 3 < N) row_start[i0 + 3] = excl;
    if (t == 255) bsum[blockIdx.x] = val;
}

__global__ __launch_bounds__(1024) void scan2_kernel(int* __restrict__ bsum, int nb)
{
    __shared__ int sh[1024];
    const int t = threadIdx.x;
    int v = (t < nb) ? bsum[t] : 0;
    sh[t] = v;
    __syncthreads();
    int val = v;
    for (int off = 1; off < 1024; off <<= 1) {
        int tmp = (t >= off) ? sh[t - off] : 0;
        __syncthreads();
        val += tmp; sh[t] = val;
        __syncthreads();
    }
    if (t < nb) bsum[t] = val - v;
}

__global__ __launch_bounds__(256) void scan3_kernel(
    int* __restrict__ row_start, const int* __restrict__ bsum, int N, int E)
{
    int i = blockIdx.x * 256 + threadIdx.x;
    if (i < N)       row_start[i] += bsum[i >> 10];
    else if (i == N) row_start[N] = E;
}

__global__ __launch_bounds__(256) void scatter_kernel(
    const int* __restrict__ idx3, const int* __restrict__ idx5,
    const int* __restrict__ row_start, int* __restrict__ cursor,
    int* __restrict__ edge_ids, int E3, int E)
{
    int e = blockIdx.x * 256 + threadIdx.x;
    if (e >= E) return;
    int n = (e < E3) ? idx3[e] : idx5[e - E3];
    int p = row_start[n] + atomicAdd(&cursor[n], 1);
    edge_ids[p] = e;
}

// ---------------- per-node attention aggregate ----------------
// one 64-lane wave per node, lane owns dims 2l,2l+1; edge loop unrolled x4
// so 4 gathers (HBM misses) are in flight per wave (MLP, Guideline 7).
__global__ __launch_bounds__(256) void agg_kernel(
    const float* __restrict__ occ3, const float* __restrict__ occ5,
    const unsigned short* __restrict__ keysb,
    const int* __restrict__ row_start, const int* __restrict__ edge_ids,
    float* __restrict__ out, int E3, int N)
{
    const int lane = threadIdx.x & 63;
    const int wid  = threadIdx.x >> 6;
    const int n = blockIdx.x * 4 + wid;
    if (n >= N) return;

    unsigned int kp = ((const unsigned int*)keysb)[(size_t)n * (D / 2) + lane];
    float kx = bf2f((unsigned short)(kp & 0xffffu));
    float ky = bf2f((unsigned short)(kp >> 16));

    const int rs = row_start[n];
    const int re = row_start[n + 1];
    const float scale = 0.0883883476483184f;   // 1/sqrt(128)

    float ax = 0.f, ay = 0.f;
    float den = 0.f;
    int i = rs;

    for (; i + 4 <= re; i += 4) {
        int e0 = edge_ids[i + 0], e1 = edge_ids[i + 1];
        int e2 = edge_ids[i + 2], e3 = edge_ids[i + 3];
        const f32x2* p0 = (e0 < E3) ? (const f32x2*)(occ3 + (size_t)e0 * D)
                                    : (const f32x2*)(occ5 + (size_t)(e0 - E3) * D);
        const f32x2* p1 = (e1 < E3) ? (const f32x2*)(occ3 + (size_t)e1 * D)
                                    : (const f32x2*)(occ5 + (size_t)(e1 - E3) * D);
        const f32x2* p2 = (e2 < E3) ? (const f32x2*)(occ3 + (size_t)e2 * D)
                                    : (const f32x2*)(occ5 + (size_t)(e2 - E3) * D);
        const f32x2* p3 = (e3 < E3) ? (const f32x2*)(occ3 + (size_t)e3 * D)
                                    : (const f32x2*)(occ5 + (size_t)(e3 - E3) * D);
        f32x2 v0 = __builtin_nontemporal_load(&p0[lane]);
        f32x2 v1 = __builtin_nontemporal_load(&p1[lane]);
        f32x2 v2 = __builtin_nontemporal_load(&p2[lane]);
        f32x2 v3 = __builtin_nontemporal_load(&p3[lane]);

        float s0 = v0[0] * kx + v0[1] * ky;
        float s1 = v1[0] * kx + v1[1] * ky;
        float s2 = v2[0] * kx + v2[1] * ky;
        float s3 = v3[0] * kx + v3[1] * ky;
        #pragma unroll
        for (int sh = 32; sh >= 1; sh >>= 1) {
            s0 += __shfl_xor(s0, sh);
            s1 += __shfl_xor(s1, sh);
            s2 += __shfl_xor(s2, sh);
            s3 += __shfl_xor(s3, sh);
        }
        float ex0 = __expf(s0 * scale);
        float ex1 = __expf(s1 * scale);
        float ex2 = __expf(s2 * scale);
        float ex3 = __expf(s3 * scale);
        den += (ex0 + ex1) + (ex2 + ex3);
        ax = fmaf(ex0, v0[0], fmaf(ex1, v1[0], fmaf(ex2, v2[0], fmaf(ex3, v3[0], ax))));
        ay = fmaf(ex0, v0[1], fmaf(ex1, v1[1], fmaf(ex2, v2[1], fmaf(ex3, v3[1], ay))));
    }
    for (; i < re; ++i) {
        int e = edge_ids[i];
        const f32x2* vp = (e < E3) ? (const f32x2*)(occ3 + (size_t)e * D)
                                   : (const f32x2*)(occ5 + (size_t)(e - E3) * D);
        f32x2 v = __builtin_nontemporal_load(&vp[lane]);
        float s = v[0] * kx + v[1] * ky;
        #pragma unroll
        for (int sh = 32; sh >= 1; sh >>= 1) s += __shfl_xor(s, sh);
        float ex = __expf(s * scale);
        den += ex;
        ax = fmaf(ex, v[0], ax);
        ay = fmaf(ex, v[1], ay);
    }

    float inv = 1.0f / (den + EPSF);
    f32x2 o; o[0] = ax * inv; o[1] = ay * inv;
    ((f32x2*)(out + (size_t)n * D))[lane] = o;
}

// ---------------- gate via MFMA ----------------
__global__ __launch_bounds__(256) void gate_mfma_kernel(
    const float* __restrict__ prev, const __bf16* __restrict__ wtg,
    const float* __restrict__ gate_b, float* __restrict__ out, int N)
{
    const int lane = threadIdx.x & 63;
    const int wid  = threadIdx.x >> 6;
    const int m0 = (blockIdx.x * 4 + wid) * 16;
    if (m0 >= N) return;
    const int lm = lane & 15;
    const int lg = lane >> 4;

    int arow = m0 + lm; if (arow >= N) arow = m0;
    const float* aprev = prev + (size_t)arow * D + lg * 8;
    const float* aagg  = out  + (size_t)arow * D + lg * 8;

    f32x4 acc[8] = {};
    #pragma unroll
    for (int kk = 0; kk < 8; ++kk) {
        const float* src = (kk < 4) ? (aprev + kk * 32) : (aagg + (kk - 4) * 32);
        float4 a0 = *(const float4*)(src);
        float4 a1 = *(const float4*)(src + 4);
        bf16x8 af;
        af[0] = (__bf16)a0.x; af[1] = (__bf16)a0.y; af[2] = (__bf16)a0.z; af[3] = (__bf16)a0.w;
        af[4] = (__bf16)a1.x; af[5] = (__bf16)a1.y; af[6] = (__bf16)a1.z; af[7] = (__bf16)a1.w;
        const int k0 = kk * 32;
        #pragma unroll
        for (int t = 0; t < 8; ++t) {
            bf16x8 bf_ = *(const bf16x8*)(wtg + (size_t)(t * 16 + lm) * 256 + k0 + lg * 8);
            acc[t] = __builtin_amdgcn_mfma_f32_16x16x32_bf16(af, bf_, acc[t], 0, 0, 0);
        }
    }

    #pragma unroll
    for (int t = 0; t < 8; ++t) {
        float bcol = gate_b[t * 16 + lm];
        #pragma unroll
        for (int r = 0; r < 4; ++r) {
            int row = m0 + lg * 4 + r;
            if (row < N) {
                size_t off = (size_t)row * D + t * 16 + lm;
                float c = acc[t][r] + bcol;
                float z = 1.0f / (1.0f + __expf(-c));
                float a = out[off];
                float p = prev[off];
                out[off] = fmaf(z, a - p, p);
            }
        }
    }
}

extern "C" void kernel_launch(void* const* d_in, const int* in_sizes, int n_in,
                              void* d_out, int out_size, void* d_ws, size_t ws_size,
                              hipStream_t stream)
{
    const float* occ3   = (const float*)d_in[0];
    const int*   idx3   = (const int*)d_in[1];
    const float* occ5   = (const float*)d_in[2];
    const int*   idx5   = (const int*)d_in[3];
    const float* prev   = (const float*)d_in[4];
    const float* attn_W = (const float*)d_in[5];
    const float* attn_b = (const float*)d_in[6];
    const float* gate_W = (const float*)d_in[7];
    const float* gate_b = (const float*)d_in[8];

    const int N  = in_sizes[4] / D;
    const int E3 = in_sizes[1];
    const int E5 = in_sizes[3];
    const int E  = E3 + E5;

    unsigned short* keysb = (unsigned short*)d_ws;
    int* row_start = (int*)(keysb + (size_t)N * D);
    int* cnt       = row_start + (N + 1);
    int* cursor    = cnt + N;
    int* bsum      = cursor + N;
    int* edge_ids  = bsum + 1025;
    __bf16* wta    = (__bf16*)(edge_ids + E);
    __bf16* wtg    = wta + 128 * 128;

    float* out = (float*)d_out;

    (void)hipMemsetAsync(cnt,    0, (size_t)N * sizeof(int), stream);
    (void)hipMemsetAsync(cursor, 0, (size_t)N * sizeof(int), stream);

    transpose_w_kernel<<<128, 256, 0, stream>>>(attn_W, gate_W, wta, wtg);

    const int nb = (N + 1023) / 1024;
    hist_kernel   <<<(E + 255) / 256, 256, 0, stream>>>(idx3, idx5, cnt, E3, E);
    scan1_kernel  <<<nb, 256, 0, stream>>>(cnt, row_start, bsum, N);
    scan2_kernel  <<<1, 1024, 0, stream>>>(bsum, nb);
    scan3_kernel  <<<(N + 256) / 256, 256, 0, stream>>>(row_start, bsum, N, E);
    scatter_kernel<<<(E + 255) / 256, 256, 0, stream>>>(idx3, idx5, row_start, cursor, edge_ids, E3, E);

    keys_mfma_kernel<<<(N + 63) / 64, 256, 0, stream>>>(prev, wta, attn_b, keysb, N);

    agg_kernel<<<(N + 3) / 4, 256, 0, stream>>>(occ3, occ5, keysb, row_start, edge_ids, out, E3, N);

    gate_mfma_kernel<<<(N + 63) / 64, 256, 0, stream>>>(prev, wtg, gate_b, out, N);
}

// Round 8
// 792.061 us; speedup vs baseline: 4.9711x; 1.0416x over previous
//
#include <hip/hip_runtime.h>
#include <math.h>

#define D 128
#define EPSF 1e-9f

typedef __bf16 bf16x8 __attribute__((ext_vector_type(8)));
typedef float  f32x4  __attribute__((ext_vector_type(4)));
typedef float  f32x2  __attribute__((ext_vector_type(2)));

static __device__ __forceinline__ float bf2f(unsigned short h) {
    union { unsigned int u; float f; } c; c.u = ((unsigned int)h) << 16;
    return c.f;
}
static __device__ __forceinline__ unsigned short f2bf(float f) {
    union { float f; unsigned int u; } c; c.f = f;
    unsigned int u = c.u + 0x7fffu + ((c.u >> 16) & 1u);
    return (unsigned short)(u >> 16);
}

// ---------------- W transpose to bf16 (tiny, once) ----------------
__global__ __launch_bounds__(256) void transpose_w_kernel(
    const float* __restrict__ attn_W, const float* __restrict__ gate_W,
    __bf16* __restrict__ wta, __bf16* __restrict__ wtg)
{
    int i = blockIdx.x * 256 + threadIdx.x;
    if (i < 128 * 128) {
        int k = i >> 7, n = i & 127;
        wta[n * 128 + k] = (__bf16)attn_W[i];
    }
    if (i < 256 * 128) {
        int k = i >> 7, n = i & 127;
        wtg[n * 256 + k] = (__bf16)gate_W[i];
    }
}

// ---------------- keys = bf16( prev @ attn_W + attn_b ), MFMA ----------------
__global__ __launch_bounds__(256) void keys_mfma_kernel(
    const float* __restrict__ prev, const __bf16* __restrict__ wta,
    const float* __restrict__ attn_b, unsigned short* __restrict__ keysb, int N)
{
    const int lane = threadIdx.x & 63;
    const int wid  = threadIdx.x >> 6;
    const int m0 = (blockIdx.x * 4 + wid) * 16;
    if (m0 >= N) return;
    const int lm = lane & 15;
    const int lg = lane >> 4;

    int arow = m0 + lm; if (arow >= N) arow = m0;
    const float* ap = prev + (size_t)arow * D + lg * 8;

    f32x4 acc[8] = {};
    #pragma unroll
    for (int kk = 0; kk < 4; ++kk) {
        float4 a0 = *(const float4*)(ap + kk * 32);
        float4 a1 = *(const float4*)(ap + kk * 32 + 4);
        bf16x8 af;
        af[0] = (__bf16)a0.x; af[1] = (__bf16)a0.y; af[2] = (__bf16)a0.z; af[3] = (__bf16)a0.w;
        af[4] = (__bf16)a1.x; af[5] = (__bf16)a1.y; af[6] = (__bf16)a1.z; af[7] = (__bf16)a1.w;
        const int k0 = kk * 32;
        #pragma unroll
        for (int t = 0; t < 8; ++t) {
            bf16x8 bf_ = *(const bf16x8*)(wta + (size_t)(t * 16 + lm) * 128 + k0 + lg * 8);
            acc[t] = __builtin_amdgcn_mfma_f32_16x16x32_bf16(af, bf_, acc[t], 0, 0, 0);
        }
    }
    __bf16* kb = (__bf16*)keysb;
    #pragma unroll
    for (int t = 0; t < 8; ++t) {
        float bcol = attn_b[t * 16 + lm];
        #pragma unroll
        for (int r = 0; r < 4; ++r) {
            int row = m0 + lg * 4 + r;
            if (row < N)
                kb[(size_t)row * D + t * 16 + lm] = (__bf16)(acc[t][r] + bcol);
        }
    }
}

// ---------------- CSR build ----------------
__global__ __launch_bounds__(256) void hist_kernel(
    const int* __restrict__ idx3, const int* __restrict__ idx5,
    int* __restrict__ cnt, int E3, int E)
{
    int e = blockIdx.x * 256 + threadIdx.x;
    if (e >= E) return;
    int n = (e < E3) ? idx3[e] : idx5[e - E3];
    atomicAdd(&cnt[n], 1);
}

__global__ __launch_bounds__(256) void scan1_kernel(
    const int* __restrict__ cnt, int* __restrict__ row_start,
    int* __restrict__ bsum, int N)
{
    __shared__ int tsum[256];
    const int t = threadIdx.x;
    const int base = blockIdx.x * 1024;
    const int i0 = base + t * 4;
    int v0 = 0, v1 = 0, v2 = 0, v3 = 0;
    if (i0 + 0 < N) v0 = cnt[i0 + 0];
    if (i0 + 1 < N) v1 = cnt[i0 + 1];
    if (i0 + 2 < N) v2 = cnt[i0 + 2];
    if (i0 + 3 < N) v3 = cnt[i0 + 3];
    int s = v0 + v1 + v2 + v3;
    tsum[t] = s;
    __syncthreads();
    int val = s;
    for (int off = 1; off < 256; off <<= 1) {
        int tmp = (t >= off) ? tsum[t - off] : 0;
        __syncthreads();
        val += tmp; tsum[t] = val;
        __syncthreads();
    }
    int excl = val - s;
    if (i0 + 0 < N) row_start[i0 + 0] = excl;            excl += v0;
    if (i0 + 1 < N) row_start[i0 + 1] = excl;            excl += v1;
    if (i0 + 2 < N) row_start[i0 + 2] = excl;            excl += v2;
    if (i0 + 3 < N) row_start[i0 + 3] = excl;
    if (t == 255) bsum[blockIdx.x] = val;
}

__global__ __launch_bounds__(1024) void scan2_kernel(int* __restrict__ bsum, int nb)
{
    __shared__ int sh[1024];
    const int t = threadIdx.x;
    int v = (t < nb) ? bsum[t] : 0;
    sh[t] = v;
    __syncthreads();
    int val = v;
    for (int off = 1; off < 1024; off <<= 1) {
        int tmp = (t >= off) ? sh[t - off] : 0;
        __syncthreads();
        val += tmp; sh[t] = val;
        __syncthreads();
    }
    if (t < nb) bsum[t] = val - v;
}

__global__ __launch_bounds__(256) void scan3_kernel(
    int* __restrict__ row_start, const int* __restrict__ bsum, int N, int E)
{
    int i = blockIdx.x * 256 + threadIdx.x;
    if (i < N)       row_start[i] += bsum[i >> 10];
    else if (i == N) row_start[N] = E;
}

__global__ __launch_bounds__(256) void scatter_kernel(
    const int* __restrict__ idx3, const int* __restrict__ idx5,
    const int* __restrict__ row_start, int* __restrict__ cursor,
    int* __restrict__ edge_ids, int E3, int E)
{
    int e = blockIdx.x * 256 + threadIdx.x;
    if (e >= E) return;
    int n = (e < E3) ? idx3[e] : idx5[e - E3];
    int p = row_start[n] + atomicAdd(&cursor[n], 1);
    edge_ids[p] = e;
}

// ---------------- per-node attention aggregate ----------------
// one 64-lane wave per node, lane owns dims 2l,2l+1.
// edge ids preloaded lane-parallel (contiguous in CSR) + shfl broadcast;
// edges processed in masked batches of 8 -> 8 gathers in flight, no serial tail.
__global__ __launch_bounds__(256) void agg_kernel(
    const float* __restrict__ occ3, const float* __restrict__ occ5,
    const unsigned short* __restrict__ keysb,
    const int* __restrict__ row_start, const int* __restrict__ edge_ids,
    unsigned int* __restrict__ aggb, int E3, int N)
{
    const int lane = threadIdx.x & 63;
    const int wid  = threadIdx.x >> 6;
    const int n = blockIdx.x * 4 + wid;
    if (n >= N) return;

    unsigned int kp = ((const unsigned int*)keysb)[(size_t)n * (D / 2) + lane];
    float kx = bf2f((unsigned short)(kp & 0xffffu));
    float ky = bf2f((unsigned short)(kp >> 16));

    const int rs = row_start[n];
    const int re = row_start[n + 1];
    const float scale = 0.0883883476483184f;   // 1/sqrt(128)

    float ax = 0.f, ay = 0.f, den = 0.f;

    for (int base = rs; base < re; base += 64) {
        const int nid = re - base;                         // ids this chunk (may exceed 64? no: min)
        const int cnt = nid < 64 ? nid : 64;
        int myid = (lane < cnt) ? edge_ids[base + lane] : 0;

        for (int j0 = 0; j0 < cnt; j0 += 8) {
            f32x2 v[8];
            #pragma unroll
            for (int j = 0; j < 8; ++j) {
                int e = __shfl(myid, j0 + j);              // garbage->0 for invalid, safe
                const f32x2* vp = (e < E3)
                    ? (const f32x2*)(occ3 + (size_t)e * D)
                    : (const f32x2*)(occ5 + (size_t)(e - E3) * D);
                v[j] = __builtin_nontemporal_load(&vp[lane]);
            }
            float s[8];
            #pragma unroll
            for (int j = 0; j < 8; ++j)
                s[j] = v[j][0] * kx + v[j][1] * ky;
            #pragma unroll
            for (int sh = 32; sh >= 1; sh >>= 1) {
                #pragma unroll
                for (int j = 0; j < 8; ++j)
                    s[j] += __shfl_xor(s[j], sh);
            }
            #pragma unroll
            for (int j = 0; j < 8; ++j) {
                float ex = (j0 + j < cnt) ? __expf(s[j] * scale) : 0.f;
                den += ex;
                ax = fmaf(ex, v[j][0], ax);
                ay = fmaf(ex, v[j][1], ay);
            }
        }
    }

    float inv = 1.0f / (den + EPSF);
    unsigned int pack = (unsigned int)f2bf(ax * inv)
                      | ((unsigned int)f2bf(ay * inv) << 16);
    aggb[(size_t)n * (D / 2) + lane] = pack;
}

// ---------------- gate via MFMA ----------------
// z = sigmoid([prev | aggn] @ gate_W + b); out = z*aggn + (1-z)*prev.
// aggn is bf16 in ws (direct MFMA A-fragments, no cvt); out = d_out, write-only.
__global__ __launch_bounds__(256) void gate_mfma_kernel(
    const float* __restrict__ prev, const __bf16* __restrict__ aggb,
    const __bf16* __restrict__ wtg, const float* __restrict__ gate_b,
    float* __restrict__ out, int N)
{
    const int lane = threadIdx.x & 63;
    const int wid  = threadIdx.x >> 6;
    const int m0 = (blockIdx.x * 4 + wid) * 16;
    if (m0 >= N) return;
    const int lm = lane & 15;
    const int lg = lane >> 4;

    int arow = m0 + lm; if (arow >= N) arow = m0;
    const float*  aprev = prev + (size_t)arow * D + lg * 8;
    const __bf16* aagg  = aggb + (size_t)arow * D + lg * 8;

    f32x4 acc[8] = {};
    #pragma unroll
    for (int kk = 0; kk < 4; ++kk) {
        float4 a0 = *(const float4*)(aprev + kk * 32);
        float4 a1 = *(const float4*)(aprev + kk * 32 + 4);
        bf16x8 af;
        af[0] = (__bf16)a0.x; af[1] = (__bf16)a0.y; af[2] = (__bf16)a0.z; af[3] = (__bf16)a0.w;
        af[4] = (__bf16)a1.x; af[5] = (__bf16)a1.y; af[6] = (__bf16)a1.z; af[7] = (__bf16)a1.w;
        const int k0 = kk * 32;
        #pragma unroll
        for (int t = 0; t < 8; ++t) {
            bf16x8 bf_ = *(const bf16x8*)(wtg + (size_t)(t * 16 + lm) * 256 + k0 + lg * 8);
            acc[t] = __builtin_amdgcn_mfma_f32_16x16x32_bf16(af, bf_, acc[t], 0, 0, 0);
        }
    }
    #pragma unroll
    for (int kk = 0; kk < 4; ++kk) {
        bf16x8 af = *(const bf16x8*)(aagg + kk * 32);
        const int k0 = 128 + kk * 32;
        #pragma unroll
        for (int t = 0; t < 8; ++t) {
            bf16x8 bf_ = *(const bf16x8*)(wtg + (size_t)(t * 16 + lm) * 256 + k0 + lg * 8);
            acc[t] = __builtin_amdgcn_mfma_f32_16x16x32_bf16(af, bf_, acc[t], 0, 0, 0);
        }
    }

    const unsigned short* aggu = (const unsigned short*)aggb;
    #pragma unroll
    for (int t = 0; t < 8; ++t) {
        float bcol = gate_b[t * 16 + lm];
        #pragma unroll
        for (int r = 0; r < 4; ++r) {
            int row = m0 + lg * 4 + r;
            if (row < N) {
                size_t off = (size_t)row * D + t * 16 + lm;
                float c = acc[t][r] + bcol;
                float z = 1.0f / (1.0f + __expf(-c));
                float a = bf2f(aggu[off]);
                float p = prev[off];
                out[off] = fmaf(z, a - p, p);
            }
        }
    }
}

extern "C" void kernel_launch(void* const* d_in, const int* in_sizes, int n_in,
                              void* d_out, int out_size, void* d_ws, size_t ws_size,
                              hipStream_t stream)
{
    const float* occ3   = (const float*)d_in[0];
    const int*   idx3   = (const int*)d_in[1];
    const float* occ5   = (const float*)d_in[2];
    const int*   idx5   = (const int*)d_in[3];
    const float* prev   = (const float*)d_in[4];
    const float* attn_W = (const float*)d_in[5];
    const float* attn_b = (const float*)d_in[6];
    const float* gate_W = (const float*)d_in[7];
    const float* gate_b = (const float*)d_in[8];

    const int N  = in_sizes[4] / D;
    const int E3 = in_sizes[1];
    const int E5 = in_sizes[3];
    const int E  = E3 + E5;

    // ws: keysb(bf16 N*D) | aggb(bf16 N*D) | row_start(N+1) | cnt(N) | cursor(N) | bsum(1025) | edge_ids(E) | wta | wtg
    unsigned short* keysb = (unsigned short*)d_ws;
    unsigned int*   aggb  = (unsigned int*)(keysb + (size_t)N * D);
    int* row_start = (int*)((unsigned short*)aggb + (size_t)N * D);
    int* cnt       = row_start + (N + 1);
    int* cursor    = cnt + N;
    int* bsum      = cursor + N;
    int* edge_ids  = bsum + 1025;
    __bf16* wta    = (__bf16*)(edge_ids + E);
    __bf16* wtg    = wta + 128 * 128;

    float* out = (float*)d_out;

    (void)hipMemsetAsync(cnt, 0, (size_t)2 * N * sizeof(int), stream);  // cnt + cursor

    transpose_w_kernel<<<128, 256, 0, stream>>>(attn_W, gate_W, wta, wtg);

    const int nb = (N + 1023) / 1024;
    hist_kernel   <<<(E + 255) / 256, 256, 0, stream>>>(idx3, idx5, cnt, E3, E);
    scan1_kernel  <<<nb, 256, 0, stream>>>(cnt, row_start, bsum, N);
    scan2_kernel  <<<1, 1024, 0, stream>>>(bsum, nb);
    scan3_kernel  <<<(N + 256) / 256, 256, 0, stream>>>(row_start, bsum, N, E);
    scatter_kernel<<<(E + 255) / 256, 256, 0, stream>>>(idx3, idx5, row_start, cursor, edge_ids, E3, E);

    keys_mfma_kernel<<<(N + 63) / 64, 256, 0, stream>>>(prev, wta, attn_b, keysb, N);

    agg_kernel<<<(N + 3) / 4, 256, 0, stream>>>(occ3, occ5, keysb, row_start, edge_ids, aggb, E3, N);

    gate_mfma_kernel<<<(N + 63) / 64, 256, 0, stream>>>(prev, (const __bf16*)aggb, wtg, gate_b, out, N);
}